// Round 3
// baseline (247.841 us; speedup 1.0000x reference)
//
#include <hip/hip_runtime.h>

#define NN 96
#define N3 (96*96*96)
#define EPS 0.0025f
#define DT  0.1f

typedef unsigned short bf16;

__device__ __forceinline__ int wm(int i){ return i==0    ? NN-1 : i-1; }
__device__ __forceinline__ int wp(int i){ return i==NN-1 ? 0    : i+1; }
__device__ __forceinline__ int IDX(int x,int y,int z){ return (x*NN+y)*NN+z; }

__device__ __forceinline__ float ldb(const bf16* __restrict__ s, int i){
  union { unsigned u; float f; } c; c.u = ((unsigned)s[i]) << 16; return c.f;
}
__device__ __forceinline__ bf16 f2b(float f){
  union { float f; unsigned u; } c; c.f = f;
  unsigned r = (c.u + 0x7fffu + ((c.u >> 16) & 1u)) >> 16;   // RNE
  return (bf16)r;
}

// m = (L v) at one point from bf16 field
__device__ __forceinline__ float Lop(const bf16* __restrict__ s,
    int xm,int x,int xp, int ym,int y,int yp, int zm,int z,int zp){
  float c = ldb(s, IDX(x,y,z));
  float sum = ldb(s,IDX(xm,y,z)) + ldb(s,IDX(xp,y,z))
            + ldb(s,IDX(x,ym,z)) + ldb(s,IDX(x,yp,z))
            + ldb(s,IDX(x,y,zm)) + ldb(s,IDX(x,y,zp));
  return fmaf(EPS, 6.0f*c - sum, c);
}

// AoS f32 [p][3] -> SoA bf16 [c][p]
__global__ void k_convert(const float* __restrict__ in, bf16* __restrict__ v){
  int i = blockIdx.x*256 + threadIdx.x;
  if (i < N3){
    v[i]      = f2b(in[3*i]);
    v[N3+i]   = f2b(in[3*i+1]);
    v[2*N3+i] = f2b(in[3*i+2]);
  }
}

// Kernel A: dis_new = dis - dt*(grad(dis)·v + v)  [dis f32], and t = t1+t2 [bf16]
// (m = Lv recomputed on the fly from bf16 v).
template<int ZERO_DIS, int LAST>
__global__ __launch_bounds__(384) void k_A(const float* __restrict__ dis,
    const bf16* __restrict__ v, float* __restrict__ dout,
    bf16* __restrict__ t, float* __restrict__ out_ilv)
{
  int z = threadIdx.x;
  int y = blockIdx.x*4 + threadIdx.y;
  int x = blockIdx.y;
  int xm=wm(x), xp=wp(x), xm2=wm(xm), xp2=wp(xp);
  int ym=wm(y), yp=wp(y), ym2=wm(ym), yp2=wp(yp);
  int zm=wm(z), zp=wp(z), zm2=wm(zm), zp2=wp(zp);
  int p = IDX(x,y,z);

  float vv[3] = { ldb(v,p), ldb(v,N3+p), ldb(v,2*N3+p) };

  // ---- dis update (f32 state) ----
  #pragma unroll
  for (int c=0;c<3;c++){
    float r;
    if (ZERO_DIS){
      r = -DT * vv[c];
    } else {
      const float* d = dis + c*N3;
      float gx = 0.5f*(d[IDX(xp,y,z)] - d[IDX(xm,y,z)]);
      float gy = 0.5f*(d[IDX(x,yp,z)] - d[IDX(x,ym,z)]);
      float gz = 0.5f*(d[IDX(x,y,zp)] - d[IDX(x,y,zm)]);
      float w  = gx*vv[0] + gy*vv[1] + gz*vv[2];
      r = d[p] - DT*(w + vv[c]);
    }
    if (LAST) out_ilv[p*3+c] = r;
    else      dout[c*N3+p]   = r;
  }
  if (LAST) return;

  // ---- t = t1 + t2 with m computed on the fly ----
  float mc[3], mxm[3], mxp[3], mym[3], myp[3], mzm[3], mzp[3];
  float vxm[3], vxp[3], vym[3], vyp[3], vzm[3], vzp[3];
  #pragma unroll
  for (int c=0;c<3;c++){
    const bf16* s = v + c*N3;
    mc [c] = Lop(s, xm,x,xp,   ym,y,yp,   zm,z,zp);
    mxm[c] = Lop(s, xm2,xm,x,  ym,y,yp,   zm,z,zp);
    mxp[c] = Lop(s, x,xp,xp2,  ym,y,yp,   zm,z,zp);
    mym[c] = Lop(s, xm,x,xp,   ym2,ym,y,  zm,z,zp);
    myp[c] = Lop(s, xm,x,xp,   y,yp,yp2,  zm,z,zp);
    mzm[c] = Lop(s, xm,x,xp,   ym,y,yp,   zm2,zm,z);
    mzp[c] = Lop(s, xm,x,xp,   ym,y,yp,   z,zp,zp2);
    vxm[c] = ldb(s,IDX(xm,y,z));  vxp[c] = ldb(s,IDX(xp,y,z));
    vym[c] = ldb(s,IDX(x,ym,z));  vyp[c] = ldb(s,IDX(x,yp,z));
    vzm[c] = ldb(s,IDX(x,y,zm));  vzp[c] = ldb(s,IDX(x,y,zp));
  }
  #pragma unroll
  for (int i=0;i<3;i++){
    float g0, g1, g2;
    if (i==0){ g0 = vxp[0]-vxm[0]; g1 = vxp[1]-vxm[1]; g2 = vxp[2]-vxm[2]; }
    else if (i==1){ g0 = vyp[0]-vym[0]; g1 = vyp[1]-vym[1]; g2 = vyp[2]-vym[2]; }
    else { g0 = vzp[0]-vzm[0]; g1 = vzp[1]-vzm[1]; g2 = vzp[2]-vzm[2]; }
    float t1 = 0.5f*(g0*mc[0] + g1*mc[1] + g2*mc[2]);
    float t2 = 0.5f*( mxp[i]*vxp[0] - mxm[i]*vxm[0]
                    + myp[i]*vyp[1] - mym[i]*vym[1]
                    + mzp[i]*vzp[2] - mzm[i]*vzm[2] );
    t[i*N3+p] = f2b(t1 + t2);
  }
}

// Kernel C: v -= dt * (I - eps*A) t   (t bf16, v bf16 in-place pointwise)
__global__ __launch_bounds__(384) void k_C(const bf16* __restrict__ t, bf16* __restrict__ v)
{
  int z = threadIdx.x;
  int y = blockIdx.x*4 + threadIdx.y;
  int x = blockIdx.y;
  int xm=wm(x), xp=wp(x);
  int ym=wm(y), yp=wp(y);
  int zm=wm(z), zp=wp(z);
  int p = IDX(x,y,z);
  #pragma unroll
  for (int c=0;c<3;c++){
    const bf16* s = t + c*N3;
    float tc = ldb(s,p);
    float sum = ldb(s,IDX(xm,y,z)) + ldb(s,IDX(xp,y,z))
              + ldb(s,IDX(x,ym,z)) + ldb(s,IDX(x,yp,z))
              + ldb(s,IDX(x,y,zm)) + ldb(s,IDX(x,y,zp));
    float u = tc - EPS*(6.0f*tc - sum);
    v[c*N3+p] = f2b(ldb(v,c*N3+p) - DT*u);
  }
}

extern "C" void kernel_launch(void* const* d_in, const int* in_sizes, int n_in,
                              void* d_out, int out_size, void* d_ws, size_t ws_size,
                              hipStream_t stream)
{
  const float* v0 = (const float*)d_in[0];
  float* out = (float*)d_out;
  char*  base = (char*)d_ws;

  bf16*  v    = (bf16*)base;                              // 3*N3 bf16
  float* disA = (float*)(base + (size_t)3*N3*2);          // 3*N3 f32
  float* disB = disA + 3*N3;                              // 3*N3 f32
  bf16*  tbuf = (bf16*)(disB + 3*N3);                     // 3*N3 bf16

  dim3 blk(96,4,1), grd(24,96,1);

  k_convert<<<(N3+255)/256, 256, 0, stream>>>(v0, v);

  float* dcur  = disA;
  float* dfree = disB;

  for (int s=0; s<10; s++){
    if (s == 0){
      k_A<1,0><<<grd, blk, 0, stream>>>(nullptr, v, dcur, tbuf, nullptr);
    } else if (s == 9){
      k_A<0,1><<<grd, blk, 0, stream>>>(dcur, v, nullptr, nullptr, out);
      break;
    } else {
      k_A<0,0><<<grd, blk, 0, stream>>>(dcur, v, dfree, tbuf, nullptr);
      float* tmp = dcur; dcur = dfree; dfree = tmp;
    }
    k_C<<<grd, blk, 0, stream>>>(tbuf, v);
  }
}